// Round 6
// baseline (266.832 us; speedup 1.0000x reference)
//
#include <hip/hip_runtime.h>
#include <hip/hip_bf16.h>

#define INF 128
#define OUTF 64
#define ALPHA 0.2f
#define EPSV 1e-6f

typedef __bf16 bf16x8 __attribute__((ext_vector_type(8)));
typedef float  f32x4  __attribute__((ext_vector_type(4)));

// ---------------------------------------------------------------------------
// k_fc (MFMA): Wh = h @ Wfc^T via 16x16x32 bf16 MFMA, 3-term bf16 split.
// Writes Wh in INTERLEAVED layout Whi[n][b][64] so both batch rows of a src
// node share one 512B block for the gather. s1/s2 fused in epilogue.
// ---------------------------------------------------------------------------
__global__ __launch_bounds__(256, 2)
void k_fc(const float* __restrict__ h, const float* __restrict__ Wfc,
          const float* __restrict__ Wattn, float* __restrict__ Whi,
          float* __restrict__ s1, float* __restrict__ s2, int BN, int N)
{
    int lane = threadIdx.x & 63;
    int wv   = blockIdx.x * 4 + (threadIdx.x >> 6);
    int base = wv * 16;
    if (base >= BN) return;
    int q = lane & 15, quad = lane >> 4;

    // B fragments: Wfc[n][k], n = t*16+q, k = kb*32 + quad*8 + j
    bf16x8 bhi[16], blo[16];
#pragma unroll
    for (int kb = 0; kb < 4; ++kb) {
#pragma unroll
        for (int t = 0; t < 4; ++t) {
            const float* wp = Wfc + (size_t)(t * 16 + q) * INF + kb * 32 + quad * 8;
            float4 w0 = *(const float4*)wp;
            float4 w1 = *(const float4*)(wp + 4);
            float wv8[8] = {w0.x, w0.y, w0.z, w0.w, w1.x, w1.y, w1.z, w1.w};
            bf16x8 hi8, lo8;
#pragma unroll
            for (int j = 0; j < 8; ++j) {
                hi8[j] = (__bf16)wv8[j];
                lo8[j] = (__bf16)(wv8[j] - (float)hi8[j]);
            }
            bhi[kb * 4 + t] = hi8;
            blo[kb * 4 + t] = lo8;
        }
    }

    f32x4 acc[4];
#pragma unroll
    for (int t = 0; t < 4; ++t) acc[t] = (f32x4){0.f, 0.f, 0.f, 0.f};

    const float* hrow = h + (size_t)(base + q) * INF + quad * 8;
#pragma unroll
    for (int kb = 0; kb < 4; ++kb) {
        float4 h0 = *(const float4*)(hrow + kb * 32);
        float4 h1 = *(const float4*)(hrow + kb * 32 + 4);
        float hv8[8] = {h0.x, h0.y, h0.z, h0.w, h1.x, h1.y, h1.z, h1.w};
        bf16x8 ahi, alo;
#pragma unroll
        for (int j = 0; j < 8; ++j) {
            ahi[j] = (__bf16)hv8[j];
            alo[j] = (__bf16)(hv8[j] - (float)ahi[j]);
        }
#pragma unroll
        for (int t = 0; t < 4; ++t) {
            acc[t] = __builtin_amdgcn_mfma_f32_16x16x32_bf16(ahi, bhi[kb * 4 + t], acc[t], 0, 0, 0);
            acc[t] = __builtin_amdgcn_mfma_f32_16x16x32_bf16(ahi, blo[kb * 4 + t], acc[t], 0, 0, 0);
            acc[t] = __builtin_amdgcn_mfma_f32_16x16x32_bf16(alo, bhi[kb * 4 + t], acc[t], 0, 0, 0);
        }
    }

    // store Whi: flat row rr = base+quad*4+r -> (b = rr>=N, n = rr - b*N),
    // Whi[n*128 + b*64 + col], col = t*16 + q
#pragma unroll
    for (int r = 0; r < 4; ++r) {
        int rr = base + quad * 4 + r;
        int b = (rr >= N) ? 1 : 0;
        int n = rr - b * N;
        float* dst = Whi + (size_t)n * 128 + b * 64 + q;
#pragma unroll
        for (int t = 0; t < 4; ++t) dst[t * 16] = acc[t][r];
    }

    // fused s1/s2
    float aS[4], aD[4];
#pragma unroll
    for (int t = 0; t < 4; ++t) {
        aS[t] = Wattn[t * 16 + q];
        aD[t] = Wattn[OUTF + t * 16 + q];
    }
    float t1[4], t2[4];
#pragma unroll
    for (int r = 0; r < 4; ++r) {
        t1[r] = acc[0][r] * aS[0] + acc[1][r] * aS[1] + acc[2][r] * aS[2] + acc[3][r] * aS[3];
        t2[r] = acc[0][r] * aD[0] + acc[1][r] * aD[1] + acc[2][r] * aD[2] + acc[3][r] * aD[3];
    }
#pragma unroll
    for (int off = 1; off <= 8; off <<= 1) {
#pragma unroll
        for (int r = 0; r < 4; ++r) {
            t1[r] += __shfl_xor(t1[r], off, 64);
            t2[r] += __shfl_xor(t2[r], off, 64);
        }
    }
    if (q == 0) {
#pragma unroll
        for (int r = 0; r < 4; ++r) {
            s1[base + quad * 4 + r] = t1[r];
            s2[base + quad * 4 + r] = t2[r];
        }
    }
}

// ---------------------------------------------------------------------------
// Histogram by dst.
// ---------------------------------------------------------------------------
__global__ __launch_bounds__(256)
void k_hist(const int* __restrict__ e_dst, int* __restrict__ deg, int E, int N)
{
    int e = blockIdx.x * 256 + threadIdx.x;
    if (e >= E) return;
    int d = e_dst[e];
    d = min(max(d, 0), N - 1);
    atomicAdd(deg + d, 1);
}

// ---------------------------------------------------------------------------
// 3-phase parallel exclusive scan over deg[N] (2048 elems per block).
// ---------------------------------------------------------------------------
__global__ __launch_bounds__(256)
void k_scan_blk(const int* __restrict__ deg, int* __restrict__ part, int N)
{
    int t = threadIdx.x, lane = t & 63, wave = t >> 6;
    int base = blockIdx.x * 2048 + t * 8;
    int s = 0;
#pragma unroll
    for (int j = 0; j < 8; ++j) { int i = base + j; if (i < N) s += deg[i]; }
#pragma unroll
    for (int off = 32; off >= 1; off >>= 1) s += __shfl_xor(s, off, 64);
    __shared__ int ws[4];
    if (lane == 0) ws[wave] = s;
    __syncthreads();
    if (t == 0) part[blockIdx.x] = ws[0] + ws[1] + ws[2] + ws[3];
}

__global__ __launch_bounds__(64)
void k_scan_mid(int* __restrict__ part, int* __restrict__ rowptrN, int nblk)
{
    int t = threadIdx.x;
    int v = (t < nblk) ? part[t] : 0;
    int orig = v;
#pragma unroll
    for (int off = 1; off < 64; off <<= 1) {
        int u = __shfl_up(v, off, 64);
        if (t >= off) v += u;
    }
    if (t < nblk) part[t] = v - orig;
    if (t == 63) *rowptrN = v;
}

__global__ __launch_bounds__(256)
void k_scan_fin(const int* __restrict__ deg, const int* __restrict__ part,
                int* __restrict__ rowptr, int* __restrict__ cursor, int N)
{
    int t = threadIdx.x, lane = t & 63, wave = t >> 6;
    int base = blockIdx.x * 2048 + t * 8;
    int vals[8]; int s = 0;
#pragma unroll
    for (int j = 0; j < 8; ++j) {
        int i = base + j;
        vals[j] = (i < N) ? deg[i] : 0;
        s += vals[j];
    }
    int inc = s;
#pragma unroll
    for (int off = 1; off < 64; off <<= 1) {
        int u = __shfl_up(inc, off, 64);
        if (lane >= off) inc += u;
    }
    __shared__ int wsum[4];
    if (lane == 63) wsum[wave] = inc;
    __syncthreads();
    int woff = 0;
#pragma unroll
    for (int w = 0; w < 4; ++w) if (w < wave) woff += wsum[w];
    int running = part[blockIdx.x] + woff + (inc - s);
#pragma unroll
    for (int j = 0; j < 8; ++j) {
        int i = base + j;
        if (i < N) { rowptr[i] = running; cursor[i] = running; }
        running += vals[j];
    }
}

// ---------------------------------------------------------------------------
// Scatter: one 16B record per edge (src, x0, x1, pad) -> single dirty line.
// ---------------------------------------------------------------------------
__global__ __launch_bounds__(256)
void k_scatter(const int* __restrict__ e_src, const int* __restrict__ e_dst,
               const float* __restrict__ s1, const float* __restrict__ s2,
               int* __restrict__ cursor, float4* __restrict__ rec, int E, int N)
{
    int e = blockIdx.x * 256 + threadIdx.x;
    if (e >= E) return;
    int d = e_dst[e];
    int s = e_src[e];
    d = min(max(d, 0), N - 1);
    s = min(max(s, 0), N - 1);
    int p = atomicAdd(cursor + d, 1);
    float e0 = s1[s] + s2[d];
    float e1 = s1[N + s] + s2[N + d];
    e0 = e0 > 0.f ? e0 : ALPHA * e0;
    e1 = e1 > 0.f ? e1 : ALPHA * e1;
    float4 r;
    r.x = __int_as_float(s);
    r.y = __expf(e0);
    r.z = __expf(e1);
    r.w = 0.f;
    rec[p] = r;
}

// ---------------------------------------------------------------------------
// k_gather v3: one wave per dst; 8 edges/iter (8 groups x 8 lanes); each lane
// gathers 4 independent float4 (64B in flight) from interleaved Whi.
// Cross-group reduce via shfl_xor(8,16,32); fused normalize + ELU store.
// ---------------------------------------------------------------------------
__global__ __launch_bounds__(256)
void k_gather(const int* __restrict__ rowptr, const float4* __restrict__ rec,
              const float* __restrict__ Whi, float* __restrict__ out, int N)
{
    int lane = threadIdx.x & 63;
    int d = blockIdx.x * 4 + (threadIdx.x >> 6);
    if (d >= N) return;
    int g = lane >> 3, q = lane & 7;

    int beg = rowptr[d];
    int end = rowptr[d + 1];
    const float4* W4 = (const float4*)Whi;   // 32 float4 per node (b0:0-15, b1:16-31)

    float4 a00 = make_float4(0.f, 0.f, 0.f, 0.f);
    float4 a01 = make_float4(0.f, 0.f, 0.f, 0.f);
    float4 a10 = make_float4(0.f, 0.f, 0.f, 0.f);
    float4 a11 = make_float4(0.f, 0.f, 0.f, 0.f);
    float n0 = 0.f, n1 = 0.f;

    for (int i = beg; i < end; i += 8) {
        int e = i + g;
        int ec = min(e, end - 1);
        float4 r = rec[ec];
        int s = __float_as_int(r.x);
        float x0 = (e < end) ? r.y : 0.f;
        float x1 = (e < end) ? r.z : 0.f;
        size_t b = (size_t)s * 32;
        float4 w00 = W4[b + q];
        float4 w01 = W4[b + 8 + q];
        float4 w10 = W4[b + 16 + q];
        float4 w11 = W4[b + 24 + q];
        a00.x += x0 * w00.x; a00.y += x0 * w00.y; a00.z += x0 * w00.z; a00.w += x0 * w00.w;
        a01.x += x0 * w01.x; a01.y += x0 * w01.y; a01.z += x0 * w01.z; a01.w += x0 * w01.w;
        a10.x += x1 * w10.x; a10.y += x1 * w10.y; a10.z += x1 * w10.z; a10.w += x1 * w10.w;
        a11.x += x1 * w11.x; a11.y += x1 * w11.y; a11.z += x1 * w11.z; a11.w += x1 * w11.w;
        n0 += x0; n1 += x1;
    }

#pragma unroll
    for (int off = 8; off <= 32; off <<= 1) {
        a00.x += __shfl_xor(a00.x, off, 64); a00.y += __shfl_xor(a00.y, off, 64);
        a00.z += __shfl_xor(a00.z, off, 64); a00.w += __shfl_xor(a00.w, off, 64);
        a01.x += __shfl_xor(a01.x, off, 64); a01.y += __shfl_xor(a01.y, off, 64);
        a01.z += __shfl_xor(a01.z, off, 64); a01.w += __shfl_xor(a01.w, off, 64);
        a10.x += __shfl_xor(a10.x, off, 64); a10.y += __shfl_xor(a10.y, off, 64);
        a10.z += __shfl_xor(a10.z, off, 64); a10.w += __shfl_xor(a10.w, off, 64);
        a11.x += __shfl_xor(a11.x, off, 64); a11.y += __shfl_xor(a11.y, off, 64);
        a11.z += __shfl_xor(a11.z, off, 64); a11.w += __shfl_xor(a11.w, off, 64);
        n0 += __shfl_xor(n0, off, 64); n1 += __shfl_xor(n1, off, 64);
    }

    if (g == 0) {
        float inv = 1.f / (n0 + EPSV);
        float4 o0 = make_float4(a00.x * inv, a00.y * inv, a00.z * inv, a00.w * inv);
        float4 o1 = make_float4(a01.x * inv, a01.y * inv, a01.z * inv, a01.w * inv);
        o0.x = o0.x > 0.f ? o0.x : expm1f(o0.x); o0.y = o0.y > 0.f ? o0.y : expm1f(o0.y);
        o0.z = o0.z > 0.f ? o0.z : expm1f(o0.z); o0.w = o0.w > 0.f ? o0.w : expm1f(o0.w);
        o1.x = o1.x > 0.f ? o1.x : expm1f(o1.x); o1.y = o1.y > 0.f ? o1.y : expm1f(o1.y);
        o1.z = o1.z > 0.f ? o1.z : expm1f(o1.z); o1.w = o1.w > 0.f ? o1.w : expm1f(o1.w);
        ((float4*)out)[(size_t)d * 16 + q] = o0;
        ((float4*)out)[(size_t)d * 16 + 8 + q] = o1;
    } else if (g == 1) {
        float inv = 1.f / (n1 + EPSV);
        float4 o0 = make_float4(a10.x * inv, a10.y * inv, a10.z * inv, a10.w * inv);
        float4 o1 = make_float4(a11.x * inv, a11.y * inv, a11.z * inv, a11.w * inv);
        o0.x = o0.x > 0.f ? o0.x : expm1f(o0.x); o0.y = o0.y > 0.f ? o0.y : expm1f(o0.y);
        o0.z = o0.z > 0.f ? o0.z : expm1f(o0.z); o0.w = o0.w > 0.f ? o0.w : expm1f(o0.w);
        o1.x = o1.x > 0.f ? o1.x : expm1f(o1.x); o1.y = o1.y > 0.f ? o1.y : expm1f(o1.y);
        o1.z = o1.z > 0.f ? o1.z : expm1f(o1.z); o1.w = o1.w > 0.f ? o1.w : expm1f(o1.w);
        ((float4*)out)[((size_t)N + d) * 16 + q] = o0;
        ((float4*)out)[((size_t)N + d) * 16 + 8 + q] = o1;
    }
}

extern "C" void kernel_launch(void* const* d_in, const int* in_sizes, int n_in,
                              void* d_out, int out_size, void* d_ws, size_t ws_size,
                              hipStream_t stream)
{
    const float* h     = (const float*)d_in[0];
    const int*   ei    = (const int*)d_in[1];
    const float* Wfc   = (const float*)d_in[2];
    const float* Wattn = (const float*)d_in[3];
    float* out = (float*)d_out;

    int BN = in_sizes[0] / INF;     // B*N = 100000
    int N  = BN / 2;                // 50000
    int E  = in_sizes[1] / 2;       // 800000

    // ws: Whi[BN*64] | rec[E]f4 | s1[BN] | s2[BN] | deg[N] | rowptr[N+1] | cursor[N+1] | part[64]
    float*  Whi    = (float*)d_ws;
    float4* rec    = (float4*)(Whi + (size_t)BN * OUTF);
    float*  s1     = (float*)(rec + E);
    float*  s2     = s1 + BN;
    int*    deg    = (int*)(s2 + BN);
    int*    rowptr = deg + N;
    int*    cursor = rowptr + N + 1;
    int*    part   = cursor + N + 1;

    int nblk = (N + 2047) / 2048;   // 25 for N=50000 (<=64 supported)

    hipMemsetAsync(deg, 0, (size_t)N * sizeof(int), stream);

    k_fc<<<(BN / 16 + 3) / 4, 256, 0, stream>>>(h, Wfc, Wattn, Whi, s1, s2, BN, N);
    k_hist<<<(E + 255) / 256, 256, 0, stream>>>(ei + E, deg, E, N);
    k_scan_blk<<<nblk, 256, 0, stream>>>(deg, part, N);
    k_scan_mid<<<1, 64, 0, stream>>>(part, rowptr + N, nblk);
    k_scan_fin<<<nblk, 256, 0, stream>>>(deg, part, rowptr, cursor, N);
    k_scatter<<<(E + 255) / 256, 256, 0, stream>>>(ei, ei + E, s1, s2, cursor, rec, E, N);
    k_gather<<<(N + 3) / 4, 256, 0, stream>>>(rowptr, rec, Whi, out, N);
}

// Round 8
// 241.987 us; speedup vs baseline: 1.1027x; 1.1027x over previous
//
#include <hip/hip_runtime.h>
#include <hip/hip_bf16.h>

#define INF 128
#define OUTF 64
#define ALPHA 0.2f
#define EPSV 1e-6f

typedef __bf16 bf16x8 __attribute__((ext_vector_type(8)));
typedef float  f32x4  __attribute__((ext_vector_type(4)));

// ---------------------------------------------------------------------------
// k_fc (MFMA): Wh = h @ Wfc^T via 16x16x32 bf16 MFMA, 3-term bf16 split.
// Stores Whb in INTERLEAVED bf16 layout Whb[n][b][64] (256B per node) so the
// gather reads half the bytes of fp32. s1/s2 (fp32, non-interleaved, R5
// contract) fused in epilogue.
// ---------------------------------------------------------------------------
__global__ __launch_bounds__(256, 2)
void k_fc(const float* __restrict__ h, const float* __restrict__ Wfc,
          const float* __restrict__ Wattn, __hip_bfloat16* __restrict__ Whb,
          float* __restrict__ s1, float* __restrict__ s2, int BN, int N)
{
    int lane = threadIdx.x & 63;
    int wv   = blockIdx.x * 4 + (threadIdx.x >> 6);
    int base = wv * 16;
    if (base >= BN) return;
    int q = lane & 15, quad = lane >> 4;

    // B fragments: Wfc[n][k], n = t*16+q, k = kb*32 + quad*8 + j
    bf16x8 bhi[16], blo[16];
#pragma unroll
    for (int kb = 0; kb < 4; ++kb) {
#pragma unroll
        for (int t = 0; t < 4; ++t) {
            const float* wp = Wfc + (size_t)(t * 16 + q) * INF + kb * 32 + quad * 8;
            float4 w0 = *(const float4*)wp;
            float4 w1 = *(const float4*)(wp + 4);
            float wv8[8] = {w0.x, w0.y, w0.z, w0.w, w1.x, w1.y, w1.z, w1.w};
            bf16x8 hi8, lo8;
#pragma unroll
            for (int j = 0; j < 8; ++j) {
                hi8[j] = (__bf16)wv8[j];
                lo8[j] = (__bf16)(wv8[j] - (float)hi8[j]);
            }
            bhi[kb * 4 + t] = hi8;
            blo[kb * 4 + t] = lo8;
        }
    }

    f32x4 acc[4];
#pragma unroll
    for (int t = 0; t < 4; ++t) acc[t] = (f32x4){0.f, 0.f, 0.f, 0.f};

    const float* hrow = h + (size_t)(base + q) * INF + quad * 8;
#pragma unroll
    for (int kb = 0; kb < 4; ++kb) {
        float4 h0 = *(const float4*)(hrow + kb * 32);
        float4 h1 = *(const float4*)(hrow + kb * 32 + 4);
        float hv8[8] = {h0.x, h0.y, h0.z, h0.w, h1.x, h1.y, h1.z, h1.w};
        bf16x8 ahi, alo;
#pragma unroll
        for (int j = 0; j < 8; ++j) {
            ahi[j] = (__bf16)hv8[j];
            alo[j] = (__bf16)(hv8[j] - (float)ahi[j]);
        }
#pragma unroll
        for (int t = 0; t < 4; ++t) {
            acc[t] = __builtin_amdgcn_mfma_f32_16x16x32_bf16(ahi, bhi[kb * 4 + t], acc[t], 0, 0, 0);
            acc[t] = __builtin_amdgcn_mfma_f32_16x16x32_bf16(ahi, blo[kb * 4 + t], acc[t], 0, 0, 0);
            acc[t] = __builtin_amdgcn_mfma_f32_16x16x32_bf16(alo, bhi[kb * 4 + t], acc[t], 0, 0, 0);
        }
    }

    // store Whb (bf16): flat row rr -> (b = rr>=N, n = rr-b*N);
    // Whb[n*128 + b*64 + col], col = t*16 + q
#pragma unroll
    for (int r = 0; r < 4; ++r) {
        int rr = base + quad * 4 + r;
        int b = (rr >= N) ? 1 : 0;
        int n = rr - b * N;
        __hip_bfloat16* dst = Whb + (size_t)n * 128 + b * 64 + q;
#pragma unroll
        for (int t = 0; t < 4; ++t) dst[t * 16] = __float2bfloat16(acc[t][r]);
    }

    // fused s1/s2 (fp32, flat over BN — R5 contract)
    float aS[4], aD[4];
#pragma unroll
    for (int t = 0; t < 4; ++t) {
        aS[t] = Wattn[t * 16 + q];
        aD[t] = Wattn[OUTF + t * 16 + q];
    }
    float t1[4], t2[4];
#pragma unroll
    for (int r = 0; r < 4; ++r) {
        t1[r] = acc[0][r] * aS[0] + acc[1][r] * aS[1] + acc[2][r] * aS[2] + acc[3][r] * aS[3];
        t2[r] = acc[0][r] * aD[0] + acc[1][r] * aD[1] + acc[2][r] * aD[2] + acc[3][r] * aD[3];
    }
#pragma unroll
    for (int off = 1; off <= 8; off <<= 1) {
#pragma unroll
        for (int r = 0; r < 4; ++r) {
            t1[r] += __shfl_xor(t1[r], off, 64);
            t2[r] += __shfl_xor(t2[r], off, 64);
        }
    }
    if (q == 0) {
#pragma unroll
        for (int r = 0; r < 4; ++r) {
            s1[base + quad * 4 + r] = t1[r];
            s2[base + quad * 4 + r] = t2[r];
        }
    }
}

// ---------------------------------------------------------------------------
// Histogram by dst (separate dispatch — R5 contract).
// ---------------------------------------------------------------------------
__global__ __launch_bounds__(256)
void k_hist(const int* __restrict__ e_dst, int* __restrict__ deg, int E, int N)
{
    int e = blockIdx.x * 256 + threadIdx.x;
    if (e >= E) return;
    int d = e_dst[e];
    d = min(max(d, 0), N - 1);
    atomicAdd(deg + d, 1);
}

// ---------------------------------------------------------------------------
// 3-phase parallel exclusive scan over deg[N] (2048 elems per block).
// ---------------------------------------------------------------------------
__global__ __launch_bounds__(256)
void k_scan_blk(const int* __restrict__ deg, int* __restrict__ part, int N)
{
    int t = threadIdx.x, lane = t & 63, wave = t >> 6;
    int base = blockIdx.x * 2048 + t * 8;
    int s = 0;
#pragma unroll
    for (int j = 0; j < 8; ++j) { int i = base + j; if (i < N) s += deg[i]; }
#pragma unroll
    for (int off = 32; off >= 1; off >>= 1) s += __shfl_xor(s, off, 64);
    __shared__ int ws[4];
    if (lane == 0) ws[wave] = s;
    __syncthreads();
    if (t == 0) part[blockIdx.x] = ws[0] + ws[1] + ws[2] + ws[3];
}

__global__ __launch_bounds__(64)
void k_scan_mid(int* __restrict__ part, int* __restrict__ rowptrN, int nblk)
{
    int t = threadIdx.x;
    int v = (t < nblk) ? part[t] : 0;
    int orig = v;
#pragma unroll
    for (int off = 1; off < 64; off <<= 1) {
        int u = __shfl_up(v, off, 64);
        if (t >= off) v += u;
    }
    if (t < nblk) part[t] = v - orig;
    if (t == 63) *rowptrN = v;
}

__global__ __launch_bounds__(256)
void k_scan_fin(const int* __restrict__ deg, const int* __restrict__ part,
                int* __restrict__ rowptr, int* __restrict__ cursor, int N)
{
    int t = threadIdx.x, lane = t & 63, wave = t >> 6;
    int base = blockIdx.x * 2048 + t * 8;
    int vals[8]; int s = 0;
#pragma unroll
    for (int j = 0; j < 8; ++j) {
        int i = base + j;
        vals[j] = (i < N) ? deg[i] : 0;
        s += vals[j];
    }
    int inc = s;
#pragma unroll
    for (int off = 1; off < 64; off <<= 1) {
        int u = __shfl_up(inc, off, 64);
        if (lane >= off) inc += u;
    }
    __shared__ int wsum[4];
    if (lane == 63) wsum[wave] = inc;
    __syncthreads();
    int woff = 0;
#pragma unroll
    for (int w = 0; w < 4; ++w) if (w < wave) woff += wsum[w];
    int running = part[blockIdx.x] + woff + (inc - s);
#pragma unroll
    for (int j = 0; j < 8; ++j) {
        int i = base + j;
        if (i < N) { rowptr[i] = running; cursor[i] = running; }
        running += vals[j];
    }
}

// ---------------------------------------------------------------------------
// Scatter: one 16B record per edge (src, x0, x1, pad) — R5 version verbatim.
// ---------------------------------------------------------------------------
__global__ __launch_bounds__(256)
void k_scatter(const int* __restrict__ e_src, const int* __restrict__ e_dst,
               const float* __restrict__ s1, const float* __restrict__ s2,
               int* __restrict__ cursor, float4* __restrict__ rec, int E, int N)
{
    int e = blockIdx.x * 256 + threadIdx.x;
    if (e >= E) return;
    int d = e_dst[e];
    int s = e_src[e];
    d = min(max(d, 0), N - 1);
    s = min(max(s, 0), N - 1);
    int p = atomicAdd(cursor + d, 1);
    float e0 = s1[s] + s2[d];
    float e1 = s1[N + s] + s2[N + d];
    e0 = e0 > 0.f ? e0 : ALPHA * e0;
    e1 = e1 > 0.f ? e1 : ALPHA * e1;
    float4 r;
    r.x = __int_as_float(s);
    r.y = __expf(e0);
    r.z = __expf(e1);
    r.w = 0.f;
    rec[p] = r;
}

// ---------------------------------------------------------------------------
// k_gather v5 (bf16): one wave per dst. Lane = (g = edge slot 0..3,
// q = 0..15): q<8 -> batch0 features 8q..8q+7, q>=8 -> batch1. Each lane
// loads ONE uint4 (8 bf16 = 16B) per edge; 8 edges/iter via 2 independent
// slots for MLP. Reduce over g with shfl_xor(16,32); g==0 lanes store
// coalesced 2x float4 after normalize + ELU. No LDS, no atomics.
// ---------------------------------------------------------------------------
__global__ __launch_bounds__(256)
void k_gather(const int* __restrict__ rowptr, const float4* __restrict__ rec,
              const unsigned int* __restrict__ Whb, float* __restrict__ out, int N)
{
    int lane = threadIdx.x & 63;
    int d = blockIdx.x * 4 + (threadIdx.x >> 6);
    if (d >= N) return;
    int g = lane >> 4, q = lane & 15;
    int b = q >> 3;                 // batch this lane handles

    int beg = rowptr[d];
    int end = rowptr[d + 1];
    const uint4* W = (const uint4*)Whb;   // 16 uint4 per node: [b0 x8][b1 x8]

    float a[8];
#pragma unroll
    for (int j = 0; j < 8; ++j) a[j] = 0.f;
    float nacc = 0.f;

    for (int i = beg; i < end; i += 8) {
        int e0 = i + g;
        int e1 = i + 4 + g;
        int ec0 = min(e0, end - 1);
        int ec1 = min(e1, end - 1);
        float4 r0 = rec[ec0];
        float4 r1 = rec[ec1];
        int s0 = __float_as_int(r0.x);
        int s1v = __float_as_int(r1.x);
        uint4 w0 = W[(size_t)s0 * 16 + q];
        uint4 w1 = W[(size_t)s1v * 16 + q];
        float x0 = (e0 < end) ? (b ? r0.z : r0.y) : 0.f;
        float x1 = (e1 < end) ? (b ? r1.z : r1.y) : 0.f;

        unsigned int u;
        u = w0.x; a[0] += x0 * __uint_as_float(u << 16); a[1] += x0 * __uint_as_float(u & 0xffff0000u);
        u = w0.y; a[2] += x0 * __uint_as_float(u << 16); a[3] += x0 * __uint_as_float(u & 0xffff0000u);
        u = w0.z; a[4] += x0 * __uint_as_float(u << 16); a[5] += x0 * __uint_as_float(u & 0xffff0000u);
        u = w0.w; a[6] += x0 * __uint_as_float(u << 16); a[7] += x0 * __uint_as_float(u & 0xffff0000u);
        u = w1.x; a[0] += x1 * __uint_as_float(u << 16); a[1] += x1 * __uint_as_float(u & 0xffff0000u);
        u = w1.y; a[2] += x1 * __uint_as_float(u << 16); a[3] += x1 * __uint_as_float(u & 0xffff0000u);
        u = w1.z; a[4] += x1 * __uint_as_float(u << 16); a[5] += x1 * __uint_as_float(u & 0xffff0000u);
        u = w1.w; a[6] += x1 * __uint_as_float(u << 16); a[7] += x1 * __uint_as_float(u & 0xffff0000u);
        nacc += x0 + x1;
    }

    // reduce over the 4 edge slots (lanes differing in bits 4..5)
#pragma unroll
    for (int off = 16; off <= 32; off <<= 1) {
#pragma unroll
        for (int j = 0; j < 8; ++j) a[j] += __shfl_xor(a[j], off, 64);
        nacc += __shfl_xor(nacc, off, 64);
    }

    if (g == 0) {
        float inv = 1.f / (nacc + EPSV);
        float v[8];
#pragma unroll
        for (int j = 0; j < 8; ++j) {
            v[j] = a[j] * inv;
            v[j] = v[j] > 0.f ? v[j] : expm1f(v[j]);
        }
        // q<8: batch0 row d, q>=8: batch1 row d; features (q&7)*8 .. +7
        size_t rowbase = ((size_t)b * N + d) * 16 + (size_t)(q & 7) * 2;
        ((float4*)out)[rowbase]     = make_float4(v[0], v[1], v[2], v[3]);
        ((float4*)out)[rowbase + 1] = make_float4(v[4], v[5], v[6], v[7]);
    }
}

extern "C" void kernel_launch(void* const* d_in, const int* in_sizes, int n_in,
                              void* d_out, int out_size, void* d_ws, size_t ws_size,
                              hipStream_t stream)
{
    const float* h     = (const float*)d_in[0];
    const int*   ei    = (const int*)d_in[1];
    const float* Wfc   = (const float*)d_in[2];
    const float* Wattn = (const float*)d_in[3];
    float* out = (float*)d_out;

    int BN = in_sizes[0] / INF;     // B*N = 100000
    int N  = BN / 2;                // 50000
    int E  = in_sizes[1] / 2;       // 800000

    // ws: Whb[BN*64] bf16 | rec[E] f4 | s1[BN] | s2[BN] | deg[N] | rowptr[N+1] | cursor[N+1] | part[64]
    __hip_bfloat16* Whb = (__hip_bfloat16*)d_ws;
    float4* rec    = (float4*)(Whb + (size_t)BN * OUTF);
    float*  s1     = (float*)(rec + E);
    float*  s2     = s1 + BN;
    int*    deg    = (int*)(s2 + BN);
    int*    rowptr = deg + N;
    int*    cursor = rowptr + N + 1;
    int*    part   = cursor + N + 1;

    int nblk = (N + 2047) / 2048;   // 25 for N=50000 (<=64 supported)

    hipMemsetAsync(deg, 0, (size_t)N * sizeof(int), stream);

    k_fc<<<(BN / 16 + 3) / 4, 256, 0, stream>>>(h, Wfc, Wattn, Whb, s1, s2, BN, N);
    k_hist<<<(E + 255) / 256, 256, 0, stream>>>(ei + E, deg, E, N);
    k_scan_blk<<<nblk, 256, 0, stream>>>(deg, part, N);
    k_scan_mid<<<1, 64, 0, stream>>>(part, rowptr + N, nblk);
    k_scan_fin<<<nblk, 256, 0, stream>>>(deg, part, rowptr, cursor, N);
    k_scatter<<<(E + 255) / 256, 256, 0, stream>>>(ei, ei + E, s1, s2, cursor, rec, E, N);
    k_gather<<<(N + 3) / 4, 256, 0, stream>>>(rowptr, rec, (const unsigned int*)Whb, out, N);
}

// Round 9
// 219.369 us; speedup vs baseline: 1.2164x; 1.1031x over previous
//
#include <hip/hip_runtime.h>
#include <hip/hip_bf16.h>

#define INF 128
#define OUTF 64
#define ALPHA 0.2f
#define EPSV 1e-6f

typedef __bf16 bf16x8 __attribute__((ext_vector_type(8)));
typedef float  f32x4  __attribute__((ext_vector_type(4)));

// ---------------------------------------------------------------------------
// k_fc (MFMA): Wh = h @ Wfc^T via 16x16x32 bf16 MFMA, 3-term bf16 split.
// Stores Whb in INTERLEAVED bf16 layout Whb[n][b][64] (256B per node).
// s1/s2 (fp32, flat over BN) fused in epilogue.  (R7 version, unchanged.)
// ---------------------------------------------------------------------------
__global__ __launch_bounds__(256, 2)
void k_fc(const float* __restrict__ h, const float* __restrict__ Wfc,
          const float* __restrict__ Wattn, __hip_bfloat16* __restrict__ Whb,
          float* __restrict__ s1, float* __restrict__ s2, int BN, int N)
{
    int lane = threadIdx.x & 63;
    int wv   = blockIdx.x * 4 + (threadIdx.x >> 6);
    int base = wv * 16;
    if (base >= BN) return;
    int q = lane & 15, quad = lane >> 4;

    bf16x8 bhi[16], blo[16];
#pragma unroll
    for (int kb = 0; kb < 4; ++kb) {
#pragma unroll
        for (int t = 0; t < 4; ++t) {
            const float* wp = Wfc + (size_t)(t * 16 + q) * INF + kb * 32 + quad * 8;
            float4 w0 = *(const float4*)wp;
            float4 w1 = *(const float4*)(wp + 4);
            float wv8[8] = {w0.x, w0.y, w0.z, w0.w, w1.x, w1.y, w1.z, w1.w};
            bf16x8 hi8, lo8;
#pragma unroll
            for (int j = 0; j < 8; ++j) {
                hi8[j] = (__bf16)wv8[j];
                lo8[j] = (__bf16)(wv8[j] - (float)hi8[j]);
            }
            bhi[kb * 4 + t] = hi8;
            blo[kb * 4 + t] = lo8;
        }
    }

    f32x4 acc[4];
#pragma unroll
    for (int t = 0; t < 4; ++t) acc[t] = (f32x4){0.f, 0.f, 0.f, 0.f};

    const float* hrow = h + (size_t)(base + q) * INF + quad * 8;
#pragma unroll
    for (int kb = 0; kb < 4; ++kb) {
        float4 h0 = *(const float4*)(hrow + kb * 32);
        float4 h1 = *(const float4*)(hrow + kb * 32 + 4);
        float hv8[8] = {h0.x, h0.y, h0.z, h0.w, h1.x, h1.y, h1.z, h1.w};
        bf16x8 ahi, alo;
#pragma unroll
        for (int j = 0; j < 8; ++j) {
            ahi[j] = (__bf16)hv8[j];
            alo[j] = (__bf16)(hv8[j] - (float)ahi[j]);
        }
#pragma unroll
        for (int t = 0; t < 4; ++t) {
            acc[t] = __builtin_amdgcn_mfma_f32_16x16x32_bf16(ahi, bhi[kb * 4 + t], acc[t], 0, 0, 0);
            acc[t] = __builtin_amdgcn_mfma_f32_16x16x32_bf16(ahi, blo[kb * 4 + t], acc[t], 0, 0, 0);
            acc[t] = __builtin_amdgcn_mfma_f32_16x16x32_bf16(alo, bhi[kb * 4 + t], acc[t], 0, 0, 0);
        }
    }

#pragma unroll
    for (int r = 0; r < 4; ++r) {
        int rr = base + quad * 4 + r;
        int b = (rr >= N) ? 1 : 0;
        int n = rr - b * N;
        __hip_bfloat16* dst = Whb + (size_t)n * 128 + b * 64 + q;
#pragma unroll
        for (int t = 0; t < 4; ++t) dst[t * 16] = __float2bfloat16(acc[t][r]);
    }

    float aS[4], aD[4];
#pragma unroll
    for (int t = 0; t < 4; ++t) {
        aS[t] = Wattn[t * 16 + q];
        aD[t] = Wattn[OUTF + t * 16 + q];
    }
    float t1[4], t2[4];
#pragma unroll
    for (int r = 0; r < 4; ++r) {
        t1[r] = acc[0][r] * aS[0] + acc[1][r] * aS[1] + acc[2][r] * aS[2] + acc[3][r] * aS[3];
        t2[r] = acc[0][r] * aD[0] + acc[1][r] * aD[1] + acc[2][r] * aD[2] + acc[3][r] * aD[3];
    }
#pragma unroll
    for (int off = 1; off <= 8; off <<= 1) {
#pragma unroll
        for (int r = 0; r < 4; ++r) {
            t1[r] += __shfl_xor(t1[r], off, 64);
            t2[r] += __shfl_xor(t2[r], off, 64);
        }
    }
    if (q == 0) {
#pragma unroll
        for (int r = 0; r < 4; ++r) {
            s1[base + quad * 4 + r] = t1[r];
            s2[base + quad * 4 + r] = t2[r];
        }
    }
}

// ---------------------------------------------------------------------------
// Histogram by dst + rank capture: rank[e] = this edge's index within its
// dst bucket (the atomicAdd return we previously threw away).
// ---------------------------------------------------------------------------
__global__ __launch_bounds__(256)
void k_hist(const int* __restrict__ e_dst, int* __restrict__ deg,
            int* __restrict__ rank, int E, int N)
{
    int e = blockIdx.x * 256 + threadIdx.x;
    if (e >= E) return;
    int d = e_dst[e];
    d = min(max(d, 0), N - 1);
    rank[e] = atomicAdd(deg + d, 1);
}

// ---------------------------------------------------------------------------
// Scan phase 1: per-block sums (2048 elems per block).
// ---------------------------------------------------------------------------
__global__ __launch_bounds__(256)
void k_scan_blk(const int* __restrict__ deg, int* __restrict__ part, int N)
{
    int t = threadIdx.x, lane = t & 63, wave = t >> 6;
    int base = blockIdx.x * 2048 + t * 8;
    int s = 0;
#pragma unroll
    for (int j = 0; j < 8; ++j) { int i = base + j; if (i < N) s += deg[i]; }
#pragma unroll
    for (int off = 32; off >= 1; off >>= 1) s += __shfl_xor(s, off, 64);
    __shared__ int ws[4];
    if (lane == 0) ws[wave] = s;
    __syncthreads();
    if (t == 0) part[blockIdx.x] = ws[0] + ws[1] + ws[2] + ws[3];
}

// ---------------------------------------------------------------------------
// Scan phase 2 (merged mid+fin): each block redundantly shfl-scans the <=64
// block partials for its own exclusive offset, then writes rowptr for its
// 2048 elements. Last block also writes rowptr[N]. No cursor array.
// ---------------------------------------------------------------------------
__global__ __launch_bounds__(256)
void k_scan_fin(const int* __restrict__ deg, const int* __restrict__ part,
                int* __restrict__ rowptr, int N, int nblk)
{
    __shared__ int s_boff, s_total;
    __shared__ int wsum[4];
    int t = threadIdx.x, lane = t & 63, wave = t >> 6;

    if (t < 64) {
        int v = (t < nblk) ? part[t] : 0;
        int inc = v;
#pragma unroll
        for (int off = 1; off < 64; off <<= 1) {
            int u = __shfl_up(inc, off, 64);
            if (t >= off) inc += u;
        }
        if (t == (int)blockIdx.x) s_boff = inc - v;   // exclusive prefix
        if (t == 63) s_total = inc;                   // grand total
    }

    int base = blockIdx.x * 2048 + t * 8;
    int vals[8]; int s = 0;
#pragma unroll
    for (int j = 0; j < 8; ++j) {
        int i = base + j;
        vals[j] = (i < N) ? deg[i] : 0;
        s += vals[j];
    }
    int inc = s;
#pragma unroll
    for (int off = 1; off < 64; off <<= 1) {
        int u = __shfl_up(inc, off, 64);
        if (lane >= off) inc += u;
    }
    if (lane == 63) wsum[wave] = inc;
    __syncthreads();

    int woff = 0;
#pragma unroll
    for (int w = 0; w < 4; ++w) if (w < wave) woff += wsum[w];
    int running = s_boff + woff + (inc - s);
#pragma unroll
    for (int j = 0; j < 8; ++j) {
        int i = base + j;
        if (i < N) rowptr[i] = running;
        running += vals[j];
    }
    if ((int)blockIdx.x == nblk - 1 && t == 0) rowptr[N] = s_total;
}

// ---------------------------------------------------------------------------
// Scatter v2 (atomic-free): p = rowptr[d] + rank[e]. One 8B record per edge:
// (src:u32, x0:bf16 | x1:bf16<<16) -> 8 records per 64B line, half the dirty
// lines of the 16B record, and no atomic round-trip in the chain.
// ---------------------------------------------------------------------------
__global__ __launch_bounds__(256)
void k_scatter(const int* __restrict__ e_src, const int* __restrict__ e_dst,
               const float* __restrict__ s1, const float* __restrict__ s2,
               const int* __restrict__ rowptr, const int* __restrict__ rank,
               uint2* __restrict__ rec, int E, int N)
{
    int e = blockIdx.x * 256 + threadIdx.x;
    if (e >= E) return;
    int d = e_dst[e];
    int s = e_src[e];
    d = min(max(d, 0), N - 1);
    s = min(max(s, 0), N - 1);
    int p = rowptr[d] + rank[e];
    float e0 = s1[s] + s2[d];
    float e1 = s1[N + s] + s2[N + d];
    e0 = e0 > 0.f ? e0 : ALPHA * e0;
    e1 = e1 > 0.f ? e1 : ALPHA * e1;
    float x0 = __expf(e0);
    float x1 = __expf(e1);
    __hip_bfloat16 b0 = __float2bfloat16(x0);
    __hip_bfloat16 b1 = __float2bfloat16(x1);
    unsigned u0 = *(unsigned short*)&b0;
    unsigned u1 = *(unsigned short*)&b1;
    rec[p] = make_uint2((unsigned)s, u0 | (u1 << 16));
}

// ---------------------------------------------------------------------------
// k_gather (bf16 Whb, 8B rec): one wave per dst. Lane = (g = edge slot 0..3,
// q = 0..15): q<8 -> batch0 features 8q.., q>=8 -> batch1. 8 edges/iter via
// 2 independent slots. Reduce over g with shfl_xor(16,32); g==0 lanes store.
// ---------------------------------------------------------------------------
__global__ __launch_bounds__(256)
void k_gather(const int* __restrict__ rowptr, const uint2* __restrict__ rec,
              const unsigned int* __restrict__ Whb, float* __restrict__ out, int N)
{
    int lane = threadIdx.x & 63;
    int d = blockIdx.x * 4 + (threadIdx.x >> 6);
    if (d >= N) return;
    int g = lane >> 4, q = lane & 15;
    int b = q >> 3;                 // batch this lane handles

    int beg = rowptr[d];
    int end = rowptr[d + 1];
    const uint4* W = (const uint4*)Whb;   // 16 uint4 per node: [b0 x8][b1 x8]

    float a[8];
#pragma unroll
    for (int j = 0; j < 8; ++j) a[j] = 0.f;
    float nacc = 0.f;

    for (int i = beg; i < end; i += 8) {
        int e0 = i + g;
        int e1 = i + 4 + g;
        int ec0 = min(e0, end - 1);
        int ec1 = min(e1, end - 1);
        uint2 r0 = rec[ec0];
        uint2 r1 = rec[ec1];
        int s0 = (int)r0.x;
        int s1v = (int)r1.x;
        uint4 w0 = W[(size_t)s0 * 16 + q];
        uint4 w1 = W[(size_t)s1v * 16 + q];
        float x0 = (e0 < end) ? __uint_as_float(b ? (r0.y & 0xffff0000u) : (r0.y << 16)) : 0.f;
        float x1 = (e1 < end) ? __uint_as_float(b ? (r1.y & 0xffff0000u) : (r1.y << 16)) : 0.f;

        unsigned int u;
        u = w0.x; a[0] += x0 * __uint_as_float(u << 16); a[1] += x0 * __uint_as_float(u & 0xffff0000u);
        u = w0.y; a[2] += x0 * __uint_as_float(u << 16); a[3] += x0 * __uint_as_float(u & 0xffff0000u);
        u = w0.z; a[4] += x0 * __uint_as_float(u << 16); a[5] += x0 * __uint_as_float(u & 0xffff0000u);
        u = w0.w; a[6] += x0 * __uint_as_float(u << 16); a[7] += x0 * __uint_as_float(u & 0xffff0000u);
        u = w1.x; a[0] += x1 * __uint_as_float(u << 16); a[1] += x1 * __uint_as_float(u & 0xffff0000u);
        u = w1.y; a[2] += x1 * __uint_as_float(u << 16); a[3] += x1 * __uint_as_float(u & 0xffff0000u);
        u = w1.z; a[4] += x1 * __uint_as_float(u << 16); a[5] += x1 * __uint_as_float(u & 0xffff0000u);
        u = w1.w; a[6] += x1 * __uint_as_float(u << 16); a[7] += x1 * __uint_as_float(u & 0xffff0000u);
        nacc += x0 + x1;
    }

#pragma unroll
    for (int off = 16; off <= 32; off <<= 1) {
#pragma unroll
        for (int j = 0; j < 8; ++j) a[j] += __shfl_xor(a[j], off, 64);
        nacc += __shfl_xor(nacc, off, 64);
    }

    if (g == 0) {
        float inv = 1.f / (nacc + EPSV);
        float v[8];
#pragma unroll
        for (int j = 0; j < 8; ++j) {
            v[j] = a[j] * inv;
            v[j] = v[j] > 0.f ? v[j] : expm1f(v[j]);
        }
        size_t rowbase = ((size_t)b * N + d) * 16 + (size_t)(q & 7) * 2;
        ((float4*)out)[rowbase]     = make_float4(v[0], v[1], v[2], v[3]);
        ((float4*)out)[rowbase + 1] = make_float4(v[4], v[5], v[6], v[7]);
    }
}

extern "C" void kernel_launch(void* const* d_in, const int* in_sizes, int n_in,
                              void* d_out, int out_size, void* d_ws, size_t ws_size,
                              hipStream_t stream)
{
    const float* h     = (const float*)d_in[0];
    const int*   ei    = (const int*)d_in[1];
    const float* Wfc   = (const float*)d_in[2];
    const float* Wattn = (const float*)d_in[3];
    float* out = (float*)d_out;

    int BN = in_sizes[0] / INF;     // B*N = 100000
    int N  = BN / 2;                // 50000
    int E  = in_sizes[1] / 2;       // 800000

    // ws: Whb[BN*64] bf16 | rec[E] u2 | s1[BN] | s2[BN] | deg[N] | rowptr[N+1] | rank[E] | part[64]
    __hip_bfloat16* Whb = (__hip_bfloat16*)d_ws;
    uint2*  rec    = (uint2*)(Whb + (size_t)BN * OUTF);
    float*  s1     = (float*)(rec + E);
    float*  s2     = s1 + BN;
    int*    deg    = (int*)(s2 + BN);
    int*    rowptr = deg + N;
    int*    rank   = rowptr + N + 1;
    int*    part   = rank + E;

    int nblk = (N + 2047) / 2048;   // 25 for N=50000 (<=64 supported)

    hipMemsetAsync(deg, 0, (size_t)N * sizeof(int), stream);

    k_fc<<<(BN / 16 + 3) / 4, 256, 0, stream>>>(h, Wfc, Wattn, Whb, s1, s2, BN, N);
    k_hist<<<(E + 255) / 256, 256, 0, stream>>>(ei + E, deg, rank, E, N);
    k_scan_blk<<<nblk, 256, 0, stream>>>(deg, part, N);
    k_scan_fin<<<nblk, 256, 0, stream>>>(deg, part, rowptr, N, nblk);
    k_scatter<<<(E + 255) / 256, 256, 0, stream>>>(ei, ei + E, s1, s2, rowptr, rank, rec, E, N);
    k_gather<<<(N + 3) / 4, 256, 0, stream>>>(rowptr, rec, (const unsigned int*)Whb, out, N);
}